// Round 1
// baseline (192.575 us; speedup 1.0000x reference)
//
#include <hip/hip_runtime.h>
#include <math.h>

#define MROWS 32768   // B*T
#define DDIM  1024
#define EDIM  64
#define BK    16
#define TILEM 64
#define NKT   (DDIM / BK)   // 64

__global__ __launch_bounds__(128)
void router_fused(const float* __restrict__ X,
                  const float* __restrict__ Wr_g,
                  const float* __restrict__ br_g,
                  const float* __restrict__ Wn_g,
                  const float* __restrict__ bn_g,
                  const float* __restrict__ U,
                  float* __restrict__ out)
{
    // GEMM phase layout: At [16][68] (1088) | WrT [16][64] (1024) | WnT [16][64] (1024)
    // Epilogue reuses smem as noisy[64][68] = 4352 floats.
    __shared__ float smem[4352];
    __shared__ int   resI[64][2];
    __shared__ float resP[64][2];

    float* At  = smem;
    float* WrT = smem + 1088;
    float* WnT = smem + 2112;

    const int t  = threadIdx.x;
    const int tx = t & 15;   // expert group: experts tx*4 .. tx*4+3
    const int ty = t >> 4;   // row group: rows ty*8 .. ty*8+7 (local)
    const int rowBase = blockIdx.x * TILEM;

    float accR[8][4], accN[8][4];
#pragma unroll
    for (int i = 0; i < 8; ++i)
#pragma unroll
        for (int j = 0; j < 4; ++j) { accR[i][j] = 0.f; accN[i][j] = 0.f; }

    // Staging maps (128 threads):
    // A: 64 rows x 16 k = 1024 floats -> 8 contiguous floats/thread
    const int arow = t >> 1;          // 0..63
    const int acol = (t & 1) * 8;     // 0 or 8
    const float* Ap = X + (size_t)(rowBase + arow) * DDIM + acol;
    // W: 16 k-rows x 64 e = 1024 floats each -> 8 contiguous floats/thread
    const int wk = t >> 3;            // 0..15
    const int we = (t & 7) * 8;       // 0..56
    const float* Rp = Wr_g + wk * EDIM + we;
    const float* Np = Wn_g + wk * EDIM + we;

    // prefetch tile 0
    float4 aA = *(const float4*)(Ap);
    float4 aB = *(const float4*)(Ap + 4);
    float4 rA = *(const float4*)(Rp);
    float4 rB = *(const float4*)(Rp + 4);
    float4 nA = *(const float4*)(Np);
    float4 nB = *(const float4*)(Np + 4);

    for (int kt = 0; kt < NKT; ++kt) {
        // write staged regs to LDS (A transposed: At[k][row], stride 68 keeps 16B align for reads)
        At[(acol+0)*68 + arow] = aA.x;
        At[(acol+1)*68 + arow] = aA.y;
        At[(acol+2)*68 + arow] = aA.z;
        At[(acol+3)*68 + arow] = aA.w;
        At[(acol+4)*68 + arow] = aB.x;
        At[(acol+5)*68 + arow] = aB.y;
        At[(acol+6)*68 + arow] = aB.z;
        At[(acol+7)*68 + arow] = aB.w;
        *(float4*)(WrT + wk*EDIM + we)     = rA;
        *(float4*)(WrT + wk*EDIM + we + 4) = rB;
        *(float4*)(WnT + wk*EDIM + we)     = nA;
        *(float4*)(WnT + wk*EDIM + we + 4) = nB;
        __syncthreads();

        // prefetch tile kt+1 (overlaps with compute below)
        if (kt + 1 < NKT) {
            const float* ap = Ap + (kt + 1) * BK;
            aA = *(const float4*)(ap);
            aB = *(const float4*)(ap + 4);
            const float* rp = Rp + (size_t)(kt + 1) * BK * EDIM;
            rA = *(const float4*)(rp);
            rB = *(const float4*)(rp + 4);
            const float* np_ = Np + (size_t)(kt + 1) * BK * EDIM;
            nA = *(const float4*)(np_);
            nB = *(const float4*)(np_ + 4);
        }

#pragma unroll
        for (int kk = 0; kk < BK; ++kk) {
            float4 a0 = *(const float4*)(At + kk*68 + ty*8);
            float4 a1 = *(const float4*)(At + kk*68 + ty*8 + 4);
            float4 wr = *(const float4*)(WrT + kk*EDIM + tx*4);
            float4 wn = *(const float4*)(WnT + kk*EDIM + tx*4);
            float a[8] = {a0.x, a0.y, a0.z, a0.w, a1.x, a1.y, a1.z, a1.w};
            float r[4] = {wr.x, wr.y, wr.z, wr.w};
            float n[4] = {wn.x, wn.y, wn.z, wn.w};
#pragma unroll
            for (int i = 0; i < 8; ++i)
#pragma unroll
                for (int j = 0; j < 4; ++j) {
                    accR[i][j] = fmaf(a[i], r[j], accR[i][j]);
                    accN[i][j] = fmaf(a[i], n[j], accN[i][j]);
                }
        }
        __syncthreads();
    }

    // ---- epilogue: bias + softplus-noise, noisy tile into LDS ----
    float4 br4 = *(const float4*)(br_g + tx*4);
    float4 bn4 = *(const float4*)(bn_g + tx*4);
    float brv[4] = {br4.x, br4.y, br4.z, br4.w};
    float bnv[4] = {bn4.x, bn4.y, bn4.z, bn4.w};

#pragma unroll
    for (int i = 0; i < 8; ++i) {
        int row = ty*8 + i;
        float4 u4 = *(const float4*)(U + (size_t)(rowBase + row) * EDIM + tx*4);
        float uv[4] = {u4.x, u4.y, u4.z, u4.w};
        float nz[4];
#pragma unroll
        for (int j = 0; j < 4; ++j) {
            float lr = accR[i][j] + brv[j];
            float ln = accN[i][j] + bnv[j];
            float sp = log1pf(expf(ln));   // softplus, matches log1p(exp(x))
            nz[j] = lr + uv[j] * sp;
        }
        *(float4*)(smem + row*68 + tx*4) = make_float4(nz[0], nz[1], nz[2], nz[3]);
    }
    __syncthreads();

    // ---- top-2 + 2-way softmax, one thread per row ----
    if (t < 64) {
        float m1 = -INFINITY, m2 = -INFINITY;
        int i1 = 0, i2 = 0;
#pragma unroll
        for (int q = 0; q < 16; ++q) {
            float4 v4 = *(const float4*)(smem + t*68 + q*4);
            float vv[4] = {v4.x, v4.y, v4.z, v4.w};
#pragma unroll
            for (int j = 0; j < 4; ++j) {
                int e = q*4 + j;
                float v = vv[j];
                if (v > m1)      { m2 = m1; i2 = i1; m1 = v; i1 = e; }
                else if (v > m2) { m2 = v; i2 = e; }
            }
        }
        float tt  = expf(m2 - m1);
        float inv = 1.0f / (1.0f + tt);
        resI[t][0] = i1; resI[t][1] = i2;
        resP[t][0] = inv; resP[t][1] = tt * inv;
        // indices output (as float values) at offset MROWS*EDIM
        float* outIdx = out + (size_t)MROWS * EDIM + (size_t)(rowBase + t) * 2;
        outIdx[0] = (float)i1;
        outIdx[1] = (float)i2;
    }
    __syncthreads();

    // ---- coalesced sparse-prob writes: 64 rows x 64 e, float4 per slot ----
#pragma unroll
    for (int q = 0; q < 8; ++q) {
        int lin = q * 128 + t;
        int row = lin >> 4;
        int e0  = (lin & 15) * 4;
        int i1 = resI[row][0], i2 = resI[row][1];
        float p1 = resP[row][0], p2 = resP[row][1];
        float o[4];
#pragma unroll
        for (int j = 0; j < 4; ++j) {
            int e = e0 + j;
            o[j] = (e == i1) ? p1 : ((e == i2) ? p2 : 0.0f);
        }
        *(float4*)(out + (size_t)(rowBase + row) * EDIM + e0) =
            make_float4(o[0], o[1], o[2], o[3]);
    }
}

extern "C" void kernel_launch(void* const* d_in, const int* in_sizes, int n_in,
                              void* d_out, int out_size, void* d_ws, size_t ws_size,
                              hipStream_t stream) {
    const float* X  = (const float*)d_in[0];  // mh_output [8,4096,1024]
    const float* Wr = (const float*)d_in[1];  // W_route   [1024,64]
    const float* br = (const float*)d_in[2];  // b_route   [64]
    const float* Wn = (const float*)d_in[3];  // W_noise   [1024,64]
    const float* bn = (const float*)d_in[4];  // b_noise   [64]
    const float* U  = (const float*)d_in[5];  // noise_u   [8,4096,64]
    (void)in_sizes; (void)n_in; (void)d_ws; (void)ws_size; // top_k=2 hardcoded
    router_fused<<<MROWS / TILEM, 128, 0, stream>>>(X, Wr, br, Wn, bn, U, (float*)d_out);
}

// Round 2
// 126.975 us; speedup vs baseline: 1.5166x; 1.5166x over previous
//
#include <hip/hip_runtime.h>
#include <math.h>

#define MROWS 32768   // B*T
#define DDIM  1024
#define EDIM  64
#define BK    16
#define TILEM 64
#define NKT   (DDIM / BK)   // 64
#define BUFSZ 3136          // At[16][68]=1088 + Wr[16][64]=1024 + Wn[16][64]=1024

__global__ __launch_bounds__(256)
void router_fused(const float* __restrict__ X,
                  const float* __restrict__ Wr_g,
                  const float* __restrict__ br_g,
                  const float* __restrict__ Wn_g,
                  const float* __restrict__ bn_g,
                  const float* __restrict__ U,
                  float* __restrict__ out)
{
    // double-buffered GEMM tiles; epilogue reuses smem[0..4351] as noisy[64][68]
    __shared__ float smem[2 * BUFSZ];
    __shared__ int   resI[64][2];
    __shared__ float resP[64][2];

    const int t  = threadIdx.x;
    const int tx = t & 15;   // expert group: experts tx*4 .. tx*4+3
    const int ty = t >> 4;   // row group: rows ty*4 .. ty*4+3 (local)
    const int rowBase = blockIdx.x * TILEM;

    float accR[4][4], accN[4][4];
#pragma unroll
    for (int i = 0; i < 4; ++i)
#pragma unroll
        for (int j = 0; j < 4; ++j) { accR[i][j] = 0.f; accN[i][j] = 0.f; }

    // Staging maps (256 threads, one float4 each per tile):
    // A: 64 rows x 16 k = 1024 floats
    const int arow = t >> 2;          // 0..63
    const int acol = (t & 3) * 4;     // 0,4,8,12
    const float* Ap = X + (size_t)(rowBase + arow) * DDIM + acol;
    // W: 16 k-rows x 64 e = 1024 floats each
    const int wk = t >> 4;            // 0..15
    const int we = (t & 15) * 4;      // 0..60
    const float* Rp = Wr_g + wk * EDIM + we;
    const float* Np = Wn_g + wk * EDIM + we;

    float4 aR, rR, nR;

    // ---- prologue: tile 0 -> buf0 ----
    aR = *(const float4*)(Ap);
    rR = *(const float4*)(Rp);
    nR = *(const float4*)(Np);
    {
        float* At  = smem;
        float* WrT = smem + 1088;
        float* WnT = smem + 2112;
        At[(acol+0)*68 + arow] = aR.x;
        At[(acol+1)*68 + arow] = aR.y;
        At[(acol+2)*68 + arow] = aR.z;
        At[(acol+3)*68 + arow] = aR.w;
        *(float4*)(WrT + wk*EDIM + we) = rR;
        *(float4*)(WnT + wk*EDIM + we) = nR;
    }
    __syncthreads();

    int cur = 0;
    for (int kt = 0; kt < NKT - 1; ++kt) {
        // issue global prefetch of tile kt+1 (latency hidden by compute below)
        aR = *(const float4*)(Ap + (kt + 1) * BK);
        rR = *(const float4*)(Rp + (size_t)(kt + 1) * BK * EDIM);
        nR = *(const float4*)(Np + (size_t)(kt + 1) * BK * EDIM);

        // compute on buf[cur]
        {
            const float* At  = smem + cur * BUFSZ;
            const float* WrT = At + 1088;
            const float* WnT = At + 2112;
#pragma unroll
            for (int kk = 0; kk < BK; ++kk) {
                float4 a4 = *(const float4*)(At  + kk*68   + ty*4);
                float4 wr = *(const float4*)(WrT + kk*EDIM + tx*4);
                float4 wn = *(const float4*)(WnT + kk*EDIM + tx*4);
                float a[4] = {a4.x, a4.y, a4.z, a4.w};
                float r[4] = {wr.x, wr.y, wr.z, wr.w};
                float n[4] = {wn.x, wn.y, wn.z, wn.w};
#pragma unroll
                for (int i = 0; i < 4; ++i)
#pragma unroll
                    for (int j = 0; j < 4; ++j) {
                        accR[i][j] = fmaf(a[i], r[j], accR[i][j]);
                        accN[i][j] = fmaf(a[i], n[j], accN[i][j]);
                    }
            }
        }

        // write prefetched tile into the other buffer (no barrier needed first:
        // previous barrier guaranteed everyone is done reading it)
        {
            float* At  = smem + (cur ^ 1) * BUFSZ;
            float* WrT = At + 1088;
            float* WnT = At + 2112;
            At[(acol+0)*68 + arow] = aR.x;
            At[(acol+1)*68 + arow] = aR.y;
            At[(acol+2)*68 + arow] = aR.z;
            At[(acol+3)*68 + arow] = aR.w;
            *(float4*)(WrT + wk*EDIM + we) = rR;
            *(float4*)(WnT + wk*EDIM + we) = nR;
        }
        __syncthreads();
        cur ^= 1;
    }

    // final tile
    {
        const float* At  = smem + cur * BUFSZ;
        const float* WrT = At + 1088;
        const float* WnT = At + 2112;
#pragma unroll
        for (int kk = 0; kk < BK; ++kk) {
            float4 a4 = *(const float4*)(At  + kk*68   + ty*4);
            float4 wr = *(const float4*)(WrT + kk*EDIM + tx*4);
            float4 wn = *(const float4*)(WnT + kk*EDIM + tx*4);
            float a[4] = {a4.x, a4.y, a4.z, a4.w};
            float r[4] = {wr.x, wr.y, wr.z, wr.w};
            float n[4] = {wn.x, wn.y, wn.z, wn.w};
#pragma unroll
            for (int i = 0; i < 4; ++i)
#pragma unroll
                for (int j = 0; j < 4; ++j) {
                    accR[i][j] = fmaf(a[i], r[j], accR[i][j]);
                    accN[i][j] = fmaf(a[i], n[j], accN[i][j]);
                }
        }
    }
    __syncthreads();   // before reusing smem as the noisy tile

    // ---- epilogue: bias + softplus-noise, noisy tile into LDS ----
    float4 br4 = *(const float4*)(br_g + tx*4);
    float4 bn4 = *(const float4*)(bn_g + tx*4);
    float brv[4] = {br4.x, br4.y, br4.z, br4.w};
    float bnv[4] = {bn4.x, bn4.y, bn4.z, bn4.w};

#pragma unroll
    for (int i = 0; i < 4; ++i) {
        int row = ty*4 + i;
        float4 u4 = *(const float4*)(U + (size_t)(rowBase + row) * EDIM + tx*4);
        float uv[4] = {u4.x, u4.y, u4.z, u4.w};
        float nz[4];
#pragma unroll
        for (int j = 0; j < 4; ++j) {
            float lr = accR[i][j] + brv[j];
            float ln = accN[i][j] + bnv[j];
            float sp = log1pf(expf(ln));   // softplus
            nz[j] = lr + uv[j] * sp;
        }
        *(float4*)(smem + row*68 + tx*4) = make_float4(nz[0], nz[1], nz[2], nz[3]);
    }
    __syncthreads();

    // ---- top-2 + 2-way softmax, one thread per row ----
    if (t < 64) {
        float m1 = -INFINITY, m2 = -INFINITY;
        int i1 = 0, i2 = 0;
#pragma unroll
        for (int q = 0; q < 16; ++q) {
            float4 v4 = *(const float4*)(smem + t*68 + q*4);
            float vv[4] = {v4.x, v4.y, v4.z, v4.w};
#pragma unroll
            for (int j = 0; j < 4; ++j) {
                int e = q*4 + j;
                float v = vv[j];
                if (v > m1)      { m2 = m1; i2 = i1; m1 = v; i1 = e; }
                else if (v > m2) { m2 = v; i2 = e; }
            }
        }
        float tt  = expf(m2 - m1);
        float inv = 1.0f / (1.0f + tt);
        resI[t][0] = i1; resI[t][1] = i2;
        resP[t][0] = inv; resP[t][1] = tt * inv;
        float* outIdx = out + (size_t)MROWS * EDIM + (size_t)(rowBase + t) * 2;
        outIdx[0] = (float)i1;
        outIdx[1] = (float)i2;
    }
    __syncthreads();

    // ---- coalesced sparse-prob writes: 64 rows x 16 float4-slots, 4 per thread ----
#pragma unroll
    for (int q = 0; q < 4; ++q) {
        int lin = q * 256 + t;
        int row = lin >> 4;
        int e0  = (lin & 15) * 4;
        int i1 = resI[row][0], i2 = resI[row][1];
        float p1 = resP[row][0], p2 = resP[row][1];
        float o[4];
#pragma unroll
        for (int j = 0; j < 4; ++j) {
            int e = e0 + j;
            o[j] = (e == i1) ? p1 : ((e == i2) ? p2 : 0.0f);
        }
        *(float4*)(out + (size_t)(rowBase + row) * EDIM + e0) =
            make_float4(o[0], o[1], o[2], o[3]);
    }
}

extern "C" void kernel_launch(void* const* d_in, const int* in_sizes, int n_in,
                              void* d_out, int out_size, void* d_ws, size_t ws_size,
                              hipStream_t stream) {
    const float* X  = (const float*)d_in[0];  // mh_output [8,4096,1024]
    const float* Wr = (const float*)d_in[1];  // W_route   [1024,64]
    const float* br = (const float*)d_in[2];  // b_route   [64]
    const float* Wn = (const float*)d_in[3];  // W_noise   [1024,64]
    const float* bn = (const float*)d_in[4];  // b_noise   [64]
    const float* U  = (const float*)d_in[5];  // noise_u   [8,4096,64]
    (void)in_sizes; (void)n_in; (void)d_ws; (void)ws_size; // top_k=2 hardcoded
    router_fused<<<MROWS / TILEM, 256, 0, stream>>>(X, Wr, br, Wn, bn, U, (float*)d_out);
}